// Round 7
// baseline (425.408 us; speedup 1.0000x reference)
//
#include <hip/hip_runtime.h>
#include <hip/hip_fp16.h>
#include <math.h>

static constexpr float NEG_SLOPE = 0.2f;
static constexpr int RR     = 4;      // count ranges (packed uint16 LDS, 50 KB)
static constexpr int NBIN2  = 25000;  // nodes per count range
static constexpr int NW     = NBIN2 / 2;
static constexpr int RF     = 8;      // fill ranges (one XCD per col region)
static constexpr int NBINF  = 12500;  // nodes per fill range
static constexpr int NWF    = NBINF / 2;
static constexpr int CHN    = 64;     // edge chunks

__device__ __forceinline__ float lrelu(float x) { return x > 0.0f ? x : NEG_SLOPE * x; }

union H8 { int4 i4; __half2 h2[4]; };

__device__ __forceinline__ void h8_to_f(int4 v, float* o) {
    H8 u; u.i4 = v;
#pragma unroll
    for (int k = 0; k < 4; ++k) {
        float2 f = __half22float2(u.h2[k]);
        o[2 * k] = f.x; o[2 * k + 1] = f.y;
    }
}

__device__ __forceinline__ int4 f_to_h8(const float* s) {
    H8 u;
#pragma unroll
    for (int k = 0; k < 4; ++k)
        u.h2[k] = __float22half2_rn(make_float2(s[2 * k], s[2 * k + 1]));
    return u.i4;
}

// ============ CSR Phase A: packed-uint16 LDS histogram (RR=4 passes) ==========
__global__ __launch_bounds__(1024) void csr_count_kernel(
    const int* __restrict__ key, unsigned short* __restrict__ cnt,
    int E, int N, int chsz)
{
    __shared__ unsigned int bins[NW];
    const int r = blockIdx.x & (RR - 1);
    const int c = blockIdx.x / RR;
    const int lo = r * NBIN2;
    const int nb = min(NBIN2, N - lo);
    if (nb <= 0) return;
    const int nw = (nb + 1) >> 1;
    for (int j = threadIdx.x; j < nw; j += 1024) bins[j] = 0;
    __syncthreads();
    const int i0 = c * chsz;
    const int i1 = min(i0 + chsz, E);
    if (i0 < i1) {
        const int nv = (i1 - i0) >> 2;  // chunk base is 16B-aligned (chsz%1024==0)
        const int4* k4 = (const int4*)(key + i0);
        for (int t = threadIdx.x; t < nv; t += 1024) {
            int4 k = k4[t];
            int b;
            b = k.x - lo; if ((unsigned)b < (unsigned)nb) atomicAdd(&bins[b >> 1], 1u << ((b & 1) * 16));
            b = k.y - lo; if ((unsigned)b < (unsigned)nb) atomicAdd(&bins[b >> 1], 1u << ((b & 1) * 16));
            b = k.z - lo; if ((unsigned)b < (unsigned)nb) atomicAdd(&bins[b >> 1], 1u << ((b & 1) * 16));
            b = k.w - lo; if ((unsigned)b < (unsigned)nb) atomicAdd(&bins[b >> 1], 1u << ((b & 1) * 16));
        }
        for (int i = i0 + (nv << 2) + threadIdx.x; i < i1; i += 1024) {
            int b = key[i] - lo;
            if ((unsigned)b < (unsigned)nb) atomicAdd(&bins[b >> 1], 1u << ((b & 1) * 16));
        }
    }
    __syncthreads();
    unsigned short* os = cnt + (size_t)c * N + lo;
    unsigned int* ow = (unsigned int*)os;  // 4B-aligned: (c*N+lo)*2 % 4 == 0
    const int full = nb >> 1;
    for (int j = threadIdx.x; j < full; j += 1024) ow[j] = bins[j];
    if ((nb & 1) && threadIdx.x == 0) os[nb - 1] = (unsigned short)(bins[nb >> 1] & 0xffffu);
}

// ============ CSR Phase B: deg + in-place chunk-offset prefix =================
__global__ __launch_bounds__(256) void degprefix_kernel(
    unsigned short* __restrict__ cnt_dst, unsigned short* __restrict__ cnt_src,
    int* __restrict__ deg_dst, int* __restrict__ deg_src, int N)
{
    int n = blockIdx.x * 256 + threadIdx.x;
    if (n >= N) return;
    int run = 0;
    for (int c = 0; c < CHN; ++c) {
        size_t idx = (size_t)c * N + n;
        int t = cnt_dst[idx];
        cnt_dst[idx] = (unsigned short)run;
        run += t;
    }
    deg_dst[n] = run;
    run = 0;
    for (int c = 0; c < CHN; ++c) {
        size_t idx = (size_t)c * N + n;
        int t = cnt_src[idx];
        cnt_src[idx] = (unsigned short)run;
        run += t;
    }
    deg_src[n] = run;
}

// ============ Two-level exclusive scan (row pointers) =========================
__global__ __launch_bounds__(256) void scan_block_kernel(
    const int* __restrict__ deg, int* __restrict__ row, int* __restrict__ part, int N)
{
    __shared__ int sm[256];
    int i = blockIdx.x * 256 + threadIdx.x;
    int v = (i < N) ? deg[i] : 0;
    sm[threadIdx.x] = v;
    __syncthreads();
#pragma unroll
    for (int off = 1; off < 256; off <<= 1) {
        int t = (threadIdx.x >= off) ? sm[threadIdx.x - off] : 0;
        __syncthreads();
        sm[threadIdx.x] += t;
        __syncthreads();
    }
    if (i < N) row[i] = sm[threadIdx.x] - v;
    if (threadIdx.x == 255) part[blockIdx.x] = sm[255];
}

__global__ __launch_bounds__(512) void scan_part_kernel(int* __restrict__ part, int nb)
{
    __shared__ int sm[512];
    int v = (threadIdx.x < nb) ? part[threadIdx.x] : 0;
    sm[threadIdx.x] = v;
    __syncthreads();
#pragma unroll
    for (int off = 1; off < 512; off <<= 1) {
        int t = (threadIdx.x >= off) ? sm[threadIdx.x - off] : 0;
        __syncthreads();
        sm[threadIdx.x] += t;
        __syncthreads();
    }
    if (threadIdx.x < nb) part[threadIdx.x] = sm[threadIdx.x] - v;
}

__global__ __launch_bounds__(256) void scan_add_kernel(
    int* __restrict__ row, const int* __restrict__ part, int N)
{
    int i = blockIdx.x * 256 + threadIdx.x;
    if (i < N) row[i] += part[i >> 8];
}

// ============ CSR Phase C: BOTH directions in one pass, RF=8 ==================
// Block (r,c): two packed ticket arrays (50 KB LDS). Reads its src/dst chunk
// once; fills col_dst where dst in range AND col_src where src in range.
// Each col region is written by exactly one XCD (blockIdx%8) -> sectors merge.
__global__ __launch_bounds__(1024) void csr_fill_both_kernel(
    const int* __restrict__ src, const int* __restrict__ dst,
    const unsigned short* __restrict__ cnt_dst, const unsigned short* __restrict__ cnt_src,
    const int* __restrict__ row_dst, const int* __restrict__ row_src,
    int* __restrict__ col_dst, int* __restrict__ col_src,
    int E, int N, int chsz)
{
    __shared__ unsigned int td[NWF];
    __shared__ unsigned int ts[NWF];
    const int r = blockIdx.x & (RF - 1);
    const int c = blockIdx.x / RF;
    const int lo = r * NBINF;
    const int nb = min(NBINF, N - lo);
    if (nb <= 0) return;
    const int nw = (nb + 1) >> 1;
    for (int j = threadIdx.x; j < nw; j += 1024) { td[j] = 0; ts[j] = 0; }
    __syncthreads();
    const int* rd = row_dst + lo;
    const int* rs = row_src + lo;
    const unsigned short* cd = cnt_dst + (size_t)c * N + lo;
    const unsigned short* cs = cnt_src + (size_t)c * N + lo;
    const int i0 = c * chsz;
    const int i1 = min(i0 + chsz, E);
    if (i0 >= i1) return;
    auto put = [&](int d, int s) {
        int b = d - lo;
        if ((unsigned)b < (unsigned)nb) {
            unsigned int old = atomicAdd(&td[b >> 1], 1u << ((b & 1) * 16));
            int t = (int)((old >> ((b & 1) * 16)) & 0xffffu);
            col_dst[rd[b] + (int)cd[b] + t] = s;
        }
        b = s - lo;
        if ((unsigned)b < (unsigned)nb) {
            unsigned int old = atomicAdd(&ts[b >> 1], 1u << ((b & 1) * 16));
            int t = (int)((old >> ((b & 1) * 16)) & 0xffffu);
            col_src[rs[b] + (int)cs[b] + t] = d;
        }
    };
    const int nv = (i1 - i0) >> 2;
    const int4* s4 = (const int4*)(src + i0);
    const int4* d4 = (const int4*)(dst + i0);
    for (int t = threadIdx.x; t < nv; t += 1024) {
        int4 s = s4[t], d = d4[t];
        put(d.x, s.x); put(d.y, s.y); put(d.z, s.z); put(d.w, s.w);
    }
    for (int i = i0 + (nv << 2) + threadIdx.x; i < i1; i += 1024)
        put(dst[i], src[i]);
}

// ============ Layer 1: h0 = relu(x1 @ lin1_w^T + b) ===========================
__global__ __launch_bounds__(256) void l1h0_kernel(
    const float* __restrict__ x1, const float* __restrict__ lin1_w,
    const float* __restrict__ lin1_b, float* __restrict__ h0, int N)
{
    int n = blockIdx.x * blockDim.x + threadIdx.x;
    if (n >= N) return;
    float acc = lin1_b[0];
#pragma unroll
    for (int k = 0; k < 7; ++k) acc = fmaf(x1[n * 7 + k], lin1_w[k], acc);
    h0[n] = fmaxf(acc, 0.0f);
}

// ============ Layer-1 gather (rank-1), 8 lanes/node ===========================
__global__ __launch_bounds__(256) void gat_gather1_kernel(
    const int* __restrict__ row_start, const int* __restrict__ degv,
    const int* __restrict__ col, const float* __restrict__ h0,
    const float* __restrict__ W1, const float* __restrict__ a_src,
    const float* __restrict__ a_dst, const float* __restrict__ bias,
    float* __restrict__ x3, int N)
{
    int t = blockIdx.x * 256 + threadIdx.x;
    int n = t >> 3, lane = t & 7;
    if (n >= N) return;
    float cs[8], cd[8];
#pragma unroll
    for (int hd = 0; hd < 8; ++hd) {
        float s = 0.0f, d = 0.0f;
#pragma unroll
        for (int c = 0; c < 4; ++c) {
            s = fmaf(W1[hd * 4 + c], a_src[hd * 4 + c], s);
            d = fmaf(W1[hd * 4 + c], a_dst[hd * 4 + c], d);
        }
        cs[hd] = s; cd[hd] = d;
    }
    float h0n = h0[n];
    float wh[8], den[8], adn[8];
#pragma unroll
    for (int hd = 0; hd < 8; ++hd) {
        adn[hd] = h0n * cd[hd];
        if (lane == 0) {
            float w = __expf(lrelu(h0n * cs[hd] + adn[hd]));
            den[hd] = w; wh[hd] = w * h0n;
        } else { den[hd] = 0.0f; wh[hd] = 0.0f; }
    }
    int start = row_start[n];
    int end = start + degv[n];
    for (int e = start + lane; e < end; e += 8) {
        int s = col[e];
        if (s == n) continue;
        float hs = h0[s];
#pragma unroll
        for (int hd = 0; hd < 8; ++hd) {
            float w = __expf(lrelu(hs * cs[hd] + adn[hd]));
            den[hd] += w;
            wh[hd] = fmaf(w, hs, wh[hd]);
        }
    }
#pragma unroll
    for (int m = 1; m < 8; m <<= 1) {
#pragma unroll
        for (int hd = 0; hd < 8; ++hd) {
            den[hd] += __shfl_xor(den[hd], m);
            wh[hd]  += __shfl_xor(wh[hd], m);
        }
    }
    float fct = wh[lane] / den[lane];
    const float4 wv = ((const float4*)W1)[lane];
    const float4 bb = ((const float4*)bias)[lane];
    float4 r;
    r.x = fmaxf(fmaf(fct, wv.x, bb.x), 0.0f);
    r.y = fmaxf(fmaf(fct, wv.y, bb.y), 0.0f);
    r.z = fmaxf(fmaf(fct, wv.z, bb.z), 0.0f);
    r.w = fmaxf(fmaf(fct, wv.w, bb.w), 0.0f);
    ((float4*)x3)[(size_t)n * 8 + lane] = r;
}

// ============ Node kernels: h = x@W stored as packed fp16 rows ================
template <int IN, int HC>
__global__ __launch_bounds__(256) void gat_node_f16_kernel(
    const float* __restrict__ x, const float* __restrict__ W,
    int4* __restrict__ hp, int N)
{
    int n = blockIdx.x * blockDim.x + threadIdx.x;
    if (n >= N) return;
    float xv[IN];
#pragma unroll
    for (int k = 0; k < IN; ++k) xv[k] = x[n * IN + k];
    float hv[HC];
#pragma unroll
    for (int j = 0; j < HC; ++j) {
        float acc = 0.0f;
#pragma unroll
        for (int k = 0; k < IN; ++k) acc = fmaf(xv[k], W[k * HC + j], acc);
        hv[j] = acc;
    }
#pragma unroll
    for (int q = 0; q < HC / 8; ++q)
        hp[(size_t)n * (HC / 8) + q] = f_to_h8(hv + q * 8);
}

// ============ Layer-2 gather: H=4, fp16 rows (32 B), scores on the fly, W=8 ===
__global__ __launch_bounds__(256) void gat_gather2_kernel(
    const int* __restrict__ row_start, const int* __restrict__ degv,
    const int* __restrict__ col, const int4* __restrict__ hp,
    const float* __restrict__ a_src, const float* __restrict__ a_dst,
    const float* __restrict__ bias, float* __restrict__ xout, int N)
{
    int t = blockIdx.x * 256 + threadIdx.x;
    int n = t >> 3, lane = t & 7;
    if (n >= N) return;
    float As[16], Ad[16];
#pragma unroll
    for (int j = 0; j < 16; ++j) { As[j] = a_src[j]; Ad[j] = a_dst[j]; }
    float hn[16];
    h8_to_f(hp[(size_t)n * 2], hn);
    h8_to_f(hp[(size_t)n * 2 + 1], hn + 8);
    float ald[4];
#pragma unroll
    for (int hd = 0; hd < 4; ++hd) {
        float d = 0.0f;
#pragma unroll
        for (int c = 0; c < 4; ++c) d = fmaf(hn[hd * 4 + c], Ad[hd * 4 + c], d);
        ald[hd] = d;
    }
    float num[16], den[4];
    if (lane == 0) {
#pragma unroll
        for (int hd = 0; hd < 4; ++hd) {
            float a = 0.0f;
#pragma unroll
            for (int c = 0; c < 4; ++c) a = fmaf(hn[hd * 4 + c], As[hd * 4 + c], a);
            float w = __expf(lrelu(a + ald[hd]));
            den[hd] = w;
#pragma unroll
            for (int c = 0; c < 4; ++c) num[hd * 4 + c] = w * hn[hd * 4 + c];
        }
    } else {
#pragma unroll
        for (int j = 0; j < 16; ++j) num[j] = 0.0f;
#pragma unroll
        for (int hd = 0; hd < 4; ++hd) den[hd] = 0.0f;
    }
    int start = row_start[n];
    int end = start + degv[n];
    for (int e = start + lane; e < end; e += 8) {
        int s = col[e];
        if (s == n) continue;
        float hs[16];
        h8_to_f(hp[(size_t)s * 2], hs);
        h8_to_f(hp[(size_t)s * 2 + 1], hs + 8);
#pragma unroll
        for (int hd = 0; hd < 4; ++hd) {
            float a = 0.0f;
#pragma unroll
            for (int c = 0; c < 4; ++c) a = fmaf(hs[hd * 4 + c], As[hd * 4 + c], a);
            float w = __expf(lrelu(a + ald[hd]));
            den[hd] += w;
#pragma unroll
            for (int c = 0; c < 4; ++c) num[hd * 4 + c] = fmaf(w, hs[hd * 4 + c], num[hd * 4 + c]);
        }
    }
#pragma unroll
    for (int m = 1; m < 8; m <<= 1) {
#pragma unroll
        for (int hd = 0; hd < 4; ++hd) den[hd] += __shfl_xor(den[hd], m);
#pragma unroll
        for (int j = 0; j < 16; ++j) num[j] += __shfl_xor(num[j], m);
    }
    if (lane < 4) {
        float inv = 1.0f / den[lane];
        const float4 bb = ((const float4*)bias)[lane];
        float4 r;
        r.x = fmaxf(fmaf(num[lane * 4 + 0], inv, bb.x), 0.0f);
        r.y = fmaxf(fmaf(num[lane * 4 + 1], inv, bb.y), 0.0f);
        r.z = fmaxf(fmaf(num[lane * 4 + 2], inv, bb.z), 0.0f);
        r.w = fmaxf(fmaf(num[lane * 4 + 3], inv, bb.w), 0.0f);
        ((float4*)xout)[(size_t)n * 4 + lane] = r;
    }
}

// ============ Layer-3 gather: H=2, fp16 rows (16 B), W=4, fp16 x6 out =========
__global__ __launch_bounds__(256) void gat_gather3_kernel(
    const int* __restrict__ row_start, const int* __restrict__ degv,
    const int* __restrict__ col, const int4* __restrict__ hp,
    const float* __restrict__ a_src, const float* __restrict__ a_dst,
    const float* __restrict__ bias, int4* __restrict__ x6p, int N)
{
    int t = blockIdx.x * 256 + threadIdx.x;
    int n = t >> 2, lane = t & 3;
    if (n >= N) return;
    float As[8], Ad[8];
#pragma unroll
    for (int j = 0; j < 8; ++j) { As[j] = a_src[j]; Ad[j] = a_dst[j]; }
    float hn[8];
    h8_to_f(hp[n], hn);
    float ald[2];
#pragma unroll
    for (int hd = 0; hd < 2; ++hd) {
        float d = 0.0f;
#pragma unroll
        for (int c = 0; c < 4; ++c) d = fmaf(hn[hd * 4 + c], Ad[hd * 4 + c], d);
        ald[hd] = d;
    }
    float num[8], den[2];
    if (lane == 0) {
#pragma unroll
        for (int hd = 0; hd < 2; ++hd) {
            float a = 0.0f;
#pragma unroll
            for (int c = 0; c < 4; ++c) a = fmaf(hn[hd * 4 + c], As[hd * 4 + c], a);
            float w = __expf(lrelu(a + ald[hd]));
            den[hd] = w;
#pragma unroll
            for (int c = 0; c < 4; ++c) num[hd * 4 + c] = w * hn[hd * 4 + c];
        }
    } else {
#pragma unroll
        for (int j = 0; j < 8; ++j) num[j] = 0.0f;
        den[0] = den[1] = 0.0f;
    }
    int start = row_start[n];
    int end = start + degv[n];
    for (int e = start + lane; e < end; e += 4) {
        int s = col[e];
        if (s == n) continue;
        float hs[8];
        h8_to_f(hp[s], hs);
#pragma unroll
        for (int hd = 0; hd < 2; ++hd) {
            float a = 0.0f;
#pragma unroll
            for (int c = 0; c < 4; ++c) a = fmaf(hs[hd * 4 + c], As[hd * 4 + c], a);
            float w = __expf(lrelu(a + ald[hd]));
            den[hd] += w;
#pragma unroll
            for (int c = 0; c < 4; ++c) num[hd * 4 + c] = fmaf(w, hs[hd * 4 + c], num[hd * 4 + c]);
        }
    }
#pragma unroll
    for (int m = 1; m < 4; m <<= 1) {
        den[0] += __shfl_xor(den[0], m);
        den[1] += __shfl_xor(den[1], m);
#pragma unroll
        for (int j = 0; j < 8; ++j) num[j] += __shfl_xor(num[j], m);
    }
    if (lane == 0) {
        float o[8];
        float i0 = 1.0f / den[0], i1 = 1.0f / den[1];
#pragma unroll
        for (int c = 0; c < 4; ++c) {
            o[c]     = fmaxf(fmaf(num[c], i0, bias[c]), 0.0f);
            o[4 + c] = fmaxf(fmaf(num[4 + c], i1, bias[4 + c]), 0.0f);
        }
        x6p[n] = f_to_h8(o);
    }
}

// ============ Final scoring: by-src CSR, fp16 x6, W=4 =========================
__global__ __launch_bounds__(256) void score_gather_kernel(
    const int* __restrict__ row_start, const int* __restrict__ degv,
    const int* __restrict__ col, const int4* __restrict__ x6p,
    const float* __restrict__ lin2_w, float* __restrict__ out, int N)
{
    int t = blockIdx.x * 256 + threadIdx.x;
    int n = t >> 2, lane = t & 3;
    if (n >= N) return;
    float sx[8];
    h8_to_f(x6p[n], sx);
    float loc, r[8];
    int sc = 0;
    if (lane == 0) {
        loc = 0.0f;
#pragma unroll
        for (int j = 0; j < 8; ++j) { loc = fmaf(sx[j], sx[j], loc); r[j] = sx[j]; }
    } else {
        loc = 0.0f;
#pragma unroll
        for (int j = 0; j < 8; ++j) r[j] = 0.0f;
    }
    int start = row_start[n];
    int dg = degv[n];
    int end = start + dg;
    for (int e = start + lane; e < end; e += 4) {
        int d = col[e];
        if (d == n) { ++sc; continue; }
        float dx[8];
        h8_to_f(x6p[d], dx);
#pragma unroll
        for (int j = 0; j < 8; ++j) { loc = fmaf(sx[j], dx[j], loc); r[j] += dx[j]; }
    }
#pragma unroll
    for (int m = 1; m < 4; m <<= 1) {
        loc += __shfl_xor(loc, m);
        sc  += __shfl_xor(sc, m);
#pragma unroll
        for (int j = 0; j < 8; ++j) r[j] += __shfl_xor(r[j], m);
    }
    if (lane == 0) {
        float invd = 1.0f / (1.0f + (float)(dg - sc));
        float g = 0.0f;
#pragma unroll
        for (int j = 0; j < 8; ++j) g = fmaf(r[j], lin2_w[j], g);
        out[n] = (loc + g) * invd;
    }
}

extern "C" void kernel_launch(void* const* d_in, const int* in_sizes, int n_in,
                              void* d_out, int out_size, void* d_ws, size_t ws_size,
                              hipStream_t stream)
{
    const float* x1     = (const float*)d_in[0];
    const int*   ei     = (const int*)d_in[2];
    const float* lin1_w = (const float*)d_in[4];
    const float* lin1_b = (const float*)d_in[5];
    const float* lin2_w = (const float*)d_in[6];
    const float* W1     = (const float*)d_in[7];
    const float* a_src1 = (const float*)d_in[8];
    const float* a_dst1 = (const float*)d_in[9];
    const float* b1     = (const float*)d_in[10];
    const float* W2     = (const float*)d_in[11];
    const float* a_src2 = (const float*)d_in[12];
    const float* a_dst2 = (const float*)d_in[13];
    const float* b2     = (const float*)d_in[14];
    const float* W3     = (const float*)d_in[15];
    const float* a_src3 = (const float*)d_in[16];
    const float* a_dst3 = (const float*)d_in[17];
    const float* b3     = (const float*)d_in[18];
    float* out = (float*)d_out;

    const int N = in_sizes[0] / 7;   // 100000
    const int E = in_sizes[2] / 2;   // 3200000
    const int* src = ei;
    const int* dst = ei + E;

    // ---- workspace layout ----
    size_t Ns = (size_t)N, Es = (size_t)E;
    int* ideg_dst = (int*)d_ws;
    int* ideg_src = ideg_dst + Ns;
    int* irow_dst = ideg_src + Ns;
    int* irow_src = irow_dst + Ns;
    int* ipart    = irow_src + Ns;        // 512 + 512
    int* icol_dst = ipart + 1024;
    int* icol_src = icol_dst + Es;
    float* f = (float*)(icol_src + Es);   // 80N float region
    // cnt arrays (2 * CHN*N uint16 = 64N floats) alias f[0,64N); die after fill
    unsigned short* cnt_dst = (unsigned short*)f;
    unsigned short* cnt_src = cnt_dst + (size_t)CHN * Ns;
    // float/fp16 buffers, all born after the fill (disjoint; total 65N <= 80N):
    float* h0  = f;                        // [0, N)
    float* x3  = f + Ns;                   // [N, 33N)      fp32 [N,32]
    int4*  h2p = (int4*)(f + 33 * Ns);     // [33N, 41N)    fp16 [N,16] (32 B rows)
    float* x4  = f + 41 * Ns;              // [41N, 57N)    fp32 [N,16]
    int4*  h3p = (int4*)(f + 57 * Ns);     // [57N, 61N)    fp16 [N,8]  (16 B rows)
    int4*  x6p = (int4*)(f + 61 * Ns);     // [61N, 65N)    fp16 [N,8]

    const int TB = 256;
    const int gN = (N + TB - 1) / TB;
    const int g8 = (8 * N + TB - 1) / TB;
    const int g4 = (4 * N + TB - 1) / TB;
    const int nb = gN;                                     // scan blocks (<=512)
    const int chsz = ((E + CHN - 1) / CHN + 1023) & ~1023; // 1024-multiple
    const int gC = RR * CHN;                               // 256 count blocks
    const int gF = RF * CHN;                               // 512 fill blocks

    // ---- CSR build ----
    csr_count_kernel<<<gC, 1024, 0, stream>>>(dst, cnt_dst, E, N, chsz);
    csr_count_kernel<<<gC, 1024, 0, stream>>>(src, cnt_src, E, N, chsz);
    degprefix_kernel<<<gN, TB, 0, stream>>>(cnt_dst, cnt_src, ideg_dst, ideg_src, N);
    scan_block_kernel<<<nb, 256, 0, stream>>>(ideg_dst, irow_dst, ipart, N);
    scan_part_kernel<<<1, 512, 0, stream>>>(ipart, nb);
    scan_add_kernel<<<nb, 256, 0, stream>>>(irow_dst, ipart, N);
    scan_block_kernel<<<nb, 256, 0, stream>>>(ideg_src, irow_src, ipart + 512, N);
    scan_part_kernel<<<1, 512, 0, stream>>>(ipart + 512, nb);
    scan_add_kernel<<<nb, 256, 0, stream>>>(irow_src, ipart + 512, N);
    csr_fill_both_kernel<<<gF, 1024, 0, stream>>>(src, dst, cnt_dst, cnt_src,
                                                  irow_dst, irow_src,
                                                  icol_dst, icol_src, E, N, chsz);

    // ---- Layer 1: rank-1 fast path ----
    l1h0_kernel<<<gN, TB, 0, stream>>>(x1, lin1_w, lin1_b, h0, N);
    gat_gather1_kernel<<<g8, TB, 0, stream>>>(irow_dst, ideg_dst, icol_dst,
                                              h0, W1, a_src1, a_dst1, b1, x3, N);

    // ---- Layer 2: [N,32] -> [N,16], H=4 ----
    gat_node_f16_kernel<32, 16><<<gN, TB, 0, stream>>>(x3, W2, h2p, N);
    gat_gather2_kernel<<<g8, TB, 0, stream>>>(irow_dst, ideg_dst, icol_dst,
                                              h2p, a_src2, a_dst2, b2, x4, N);

    // ---- Layer 3: [N,16] -> [N,8], H=2 ----
    gat_node_f16_kernel<16, 8><<<gN, TB, 0, stream>>>(x4, W3, h3p, N);
    gat_gather3_kernel<<<g4, TB, 0, stream>>>(irow_dst, ideg_dst, icol_dst,
                                              h3p, a_src3, a_dst3, b3, x6p, N);

    // ---- Final scoring (by-src CSR) ----
    score_gather_kernel<<<g4, TB, 0, stream>>>(irow_src, ideg_src, icol_src,
                                               x6p, lin2_w, out, N);
}

// Round 8
// 291.107 us; speedup vs baseline: 1.4613x; 1.4613x over previous
//
#include <hip/hip_runtime.h>
#include <hip/hip_fp16.h>
#include <math.h>

static constexpr float NEG_SLOPE = 0.2f;
static constexpr int P      = 256;    // node ranges for bucket sort
static constexpr int MAXNPR = 400;    // max nodes/range (N <= 102400)
static constexpr int CAP    = 14800;  // staging capacity per range (edges); mean 12.5K, +20 sigma
static constexpr int PB     = 256;    // phase-1 partition blocks

__device__ __forceinline__ float lrelu(float x) { return x > 0.0f ? x : NEG_SLOPE * x; }

// divide by runtime npr via magic multiply (+/-1 fixup); valid for x < 2^31
__device__ __forceinline__ void dm(int x, unsigned int mg, int npr, int& r, int& lk) {
    r = (int)__umulhi((unsigned int)x, mg);
    lk = x - r * npr;
    if (lk >= npr) { lk -= npr; ++r; }
    else if (lk < 0) { lk += npr; --r; }
}

union H8 { int4 i4; __half2 h2[4]; };

__device__ __forceinline__ void h8_to_f(int4 v, float* o) {
    H8 u; u.i4 = v;
#pragma unroll
    for (int k = 0; k < 4; ++k) {
        float2 f = __half22float2(u.h2[k]);
        o[2 * k] = f.x; o[2 * k + 1] = f.y;
    }
}

__device__ __forceinline__ int4 f_to_h8(const float* s) {
    H8 u;
#pragma unroll
    for (int k = 0; k < 4; ++k)
        u.h2[k] = __float22half2_rn(make_float2(s[2 * k], s[2 * k + 1]));
    return u.i4;
}

// ============ Build Phase 1: partition edges into P range buckets =============
// Each (block,range) segment of staging is written by exactly one block ->
// sectors are block-private -> they merge in that CU's L2 (no 32B-per-4B
// amplification). Packed word: (local_key << 17) | neighbor  (N < 131072).
__global__ __launch_bounds__(256) void part_kernel(
    const int* __restrict__ src, const int* __restrict__ dst,
    unsigned int* __restrict__ stgd, unsigned int* __restrict__ stgs,
    int* __restrict__ gcount, int E, int npr, unsigned int mg, int chsz)
{
    __shared__ int cnt[2 * P];
    __shared__ int base[2 * P];
    __shared__ int tick[2 * P];
    const int c = blockIdx.x;
    const int i0 = c * chsz;
    const int i1 = min(i0 + chsz, E);
    for (int j = threadIdx.x; j < 2 * P; j += 256) cnt[j] = 0;
    __syncthreads();
    const int nv = (i1 > i0) ? ((i1 - i0) >> 2) : 0;
    const int4* s4 = (const int4*)(src + i0);
    const int4* d4 = (const int4*)(dst + i0);
    // pass A: count both directions
    for (int t = threadIdx.x; t < nv; t += 256) {
        int4 s = s4[t], d = d4[t];
        int r, lk;
        dm(d.x, mg, npr, r, lk); atomicAdd(&cnt[r], 1);
        dm(d.y, mg, npr, r, lk); atomicAdd(&cnt[r], 1);
        dm(d.z, mg, npr, r, lk); atomicAdd(&cnt[r], 1);
        dm(d.w, mg, npr, r, lk); atomicAdd(&cnt[r], 1);
        dm(s.x, mg, npr, r, lk); atomicAdd(&cnt[P + r], 1);
        dm(s.y, mg, npr, r, lk); atomicAdd(&cnt[P + r], 1);
        dm(s.z, mg, npr, r, lk); atomicAdd(&cnt[P + r], 1);
        dm(s.w, mg, npr, r, lk); atomicAdd(&cnt[P + r], 1);
    }
    for (int i = i0 + (nv << 2) + threadIdx.x; i < i1; i += 256) {
        int s = src[i], d = dst[i];
        int r, lk;
        dm(d, mg, npr, r, lk); atomicAdd(&cnt[r], 1);
        dm(s, mg, npr, r, lk); atomicAdd(&cnt[P + r], 1);
    }
    __syncthreads();
    // reserve contiguous per-(block,range) segments
    for (int j = threadIdx.x; j < 2 * P; j += 256) {
        base[j] = atomicAdd(&gcount[j], cnt[j]);
        tick[j] = 0;
    }
    __syncthreads();
    // pass B: write packed words
    auto emit = [&](int s, int d) {
        int r, lk;
        dm(d, mg, npr, r, lk);
        int t = atomicAdd(&tick[r], 1);
        stgd[(size_t)r * CAP + base[r] + t] = ((unsigned int)lk << 17) | (unsigned int)s;
        dm(s, mg, npr, r, lk);
        t = atomicAdd(&tick[P + r], 1);
        stgs[(size_t)r * CAP + base[P + r] + t] = ((unsigned int)lk << 17) | (unsigned int)d;
    };
    for (int t = threadIdx.x; t < nv; t += 256) {
        int4 s = s4[t], d = d4[t];
        emit(s.x, d.x); emit(s.y, d.y); emit(s.z, d.z); emit(s.w, d.w);
    }
    for (int i = i0 + (nv << 2) + threadIdx.x; i < i1; i += 256)
        emit(src[i], dst[i]);
}

// ============ Tiny scan: per-range edge bases (exclusive, per direction) ======
__global__ __launch_bounds__(512) void ebase_kernel(
    const int* __restrict__ gcount, int* __restrict__ ebase)
{
    __shared__ int sm[2 * P];
    int tid = threadIdx.x;
    int v = gcount[tid];
    sm[tid] = v;
    __syncthreads();
#pragma unroll
    for (int off = 1; off < P; off <<= 1) {
        int t = ((tid & (P - 1)) >= off) ? sm[tid - off] : 0;
        __syncthreads();
        sm[tid] += t;
        __syncthreads();
    }
    ebase[tid] = sm[tid] - v;  // exclusive within each direction half
}

// ============ Build Phase 2: per-range LDS counting sort -> CSR ===============
// Emits deg[], row[] AND the sorted col segment (coalesced streaming write).
__global__ __launch_bounds__(256) void build_kernel(
    const unsigned int* __restrict__ stgd, const unsigned int* __restrict__ stgs,
    const int* __restrict__ gcount, const int* __restrict__ ebase,
    int* __restrict__ col_dst, int* __restrict__ col_src,
    int* __restrict__ deg_dst, int* __restrict__ deg_src,
    int* __restrict__ row_dst, int* __restrict__ row_src,
    int N, int npr)
{
    __shared__ int cnt[MAXNPR];
    __shared__ int pref[MAXNPR];
    __shared__ int part[256];
    __shared__ int outv[CAP];
    const int dir = blockIdx.x >> 8;          // 256 ranges per direction
    const int r = blockIdx.x & (P - 1);
    const unsigned int* stg = (dir ? stgs : stgd) + (size_t)r * CAP;
    int tot = gcount[dir * P + r];
    if (tot > CAP) tot = CAP;
    const int n0 = r * npr;
    const int nb = min(npr, N - n0);
    const int tid = threadIdx.x;
    for (int j = tid; j < npr; j += 256) cnt[j] = 0;
    __syncthreads();
    for (int i = tid; i < tot; i += 256)
        atomicAdd(&cnt[stg[i] >> 17], 1);
    __syncthreads();
    // exclusive scan over cnt[0..npr): 4 contiguous bins per thread
    int b0 = tid * 4;
    int v0 = 0, v1 = 0, v2 = 0, v3 = 0;
    if (b0 + 0 < npr) v0 = cnt[b0 + 0];
    if (b0 + 1 < npr) v1 = cnt[b0 + 1];
    if (b0 + 2 < npr) v2 = cnt[b0 + 2];
    if (b0 + 3 < npr) v3 = cnt[b0 + 3];
    int s = v0 + v1 + v2 + v3;
    part[tid] = s;
    __syncthreads();
#pragma unroll
    for (int off = 1; off < 256; off <<= 1) {
        int t = (tid >= off) ? part[tid - off] : 0;
        __syncthreads();
        part[tid] += t;
        __syncthreads();
    }
    int ex = part[tid] - s;
    if (b0 + 0 < npr) pref[b0 + 0] = ex;
    if (b0 + 1 < npr) pref[b0 + 1] = ex + v0;
    if (b0 + 2 < npr) pref[b0 + 2] = ex + v0 + v1;
    if (b0 + 3 < npr) pref[b0 + 3] = ex + v0 + v1 + v2;
    __syncthreads();
    // emit deg/row (coalesced)
    int* deg = dir ? deg_src : deg_dst;
    int* row = dir ? row_src : row_dst;
    const int eb = ebase[dir * P + r];
    for (int j = tid; j < nb; j += 256) {
        deg[n0 + j] = cnt[j];
        row[n0 + j] = eb + pref[j];
    }
    __syncthreads();
    // tickets = pref (reuse cnt)
    for (int j = tid; j < npr; j += 256) cnt[j] = pref[j];
    __syncthreads();
    for (int i = tid; i < tot; i += 256) {
        unsigned int w = stg[i];
        int t = atomicAdd(&cnt[w >> 17], 1);
        outv[t] = (int)(w & 0x1FFFFu);
    }
    __syncthreads();
    int* col = (dir ? col_src : col_dst) + eb;
    for (int i = tid; i < tot; i += 256) col[i] = outv[i];
}

// ============ Layer 1: h0 = relu(x1 @ lin1_w^T + b) ===========================
__global__ __launch_bounds__(256) void l1h0_kernel(
    const float* __restrict__ x1, const float* __restrict__ lin1_w,
    const float* __restrict__ lin1_b, float* __restrict__ h0, int N)
{
    int n = blockIdx.x * blockDim.x + threadIdx.x;
    if (n >= N) return;
    float acc = lin1_b[0];
#pragma unroll
    for (int k = 0; k < 7; ++k) acc = fmaf(x1[n * 7 + k], lin1_w[k], acc);
    h0[n] = fmaxf(acc, 0.0f);
}

// ============ Layer-1 gather (rank-1), 8 lanes/node ===========================
__global__ __launch_bounds__(256) void gat_gather1_kernel(
    const int* __restrict__ row_start, const int* __restrict__ degv,
    const int* __restrict__ col, const float* __restrict__ h0,
    const float* __restrict__ W1, const float* __restrict__ a_src,
    const float* __restrict__ a_dst, const float* __restrict__ bias,
    float* __restrict__ x3, int N)
{
    int t = blockIdx.x * 256 + threadIdx.x;
    int n = t >> 3, lane = t & 7;
    if (n >= N) return;
    float cs[8], cd[8];
#pragma unroll
    for (int hd = 0; hd < 8; ++hd) {
        float s = 0.0f, d = 0.0f;
#pragma unroll
        for (int c = 0; c < 4; ++c) {
            s = fmaf(W1[hd * 4 + c], a_src[hd * 4 + c], s);
            d = fmaf(W1[hd * 4 + c], a_dst[hd * 4 + c], d);
        }
        cs[hd] = s; cd[hd] = d;
    }
    float h0n = h0[n];
    float wh[8], den[8], adn[8];
#pragma unroll
    for (int hd = 0; hd < 8; ++hd) {
        adn[hd] = h0n * cd[hd];
        if (lane == 0) {
            float w = __expf(lrelu(h0n * cs[hd] + adn[hd]));
            den[hd] = w; wh[hd] = w * h0n;
        } else { den[hd] = 0.0f; wh[hd] = 0.0f; }
    }
    int start = row_start[n];
    int end = start + degv[n];
    for (int e = start + lane; e < end; e += 8) {
        int s = col[e];
        if (s == n) continue;
        float hs = h0[s];
#pragma unroll
        for (int hd = 0; hd < 8; ++hd) {
            float w = __expf(lrelu(hs * cs[hd] + adn[hd]));
            den[hd] += w;
            wh[hd] = fmaf(w, hs, wh[hd]);
        }
    }
#pragma unroll
    for (int m = 1; m < 8; m <<= 1) {
#pragma unroll
        for (int hd = 0; hd < 8; ++hd) {
            den[hd] += __shfl_xor(den[hd], m);
            wh[hd]  += __shfl_xor(wh[hd], m);
        }
    }
    float fct = wh[lane] / den[lane];
    const float4 wv = ((const float4*)W1)[lane];
    const float4 bb = ((const float4*)bias)[lane];
    float4 r;
    r.x = fmaxf(fmaf(fct, wv.x, bb.x), 0.0f);
    r.y = fmaxf(fmaf(fct, wv.y, bb.y), 0.0f);
    r.z = fmaxf(fmaf(fct, wv.z, bb.z), 0.0f);
    r.w = fmaxf(fmaf(fct, wv.w, bb.w), 0.0f);
    ((float4*)x3)[(size_t)n * 8 + lane] = r;
}

// ============ Node kernels: h = x@W stored as packed fp16 rows ================
template <int IN, int HC>
__global__ __launch_bounds__(256) void gat_node_f16_kernel(
    const float* __restrict__ x, const float* __restrict__ W,
    int4* __restrict__ hp, int N)
{
    int n = blockIdx.x * blockDim.x + threadIdx.x;
    if (n >= N) return;
    float xv[IN];
#pragma unroll
    for (int k = 0; k < IN; ++k) xv[k] = x[n * IN + k];
    float hv[HC];
#pragma unroll
    for (int j = 0; j < HC; ++j) {
        float acc = 0.0f;
#pragma unroll
        for (int k = 0; k < IN; ++k) acc = fmaf(xv[k], W[k * HC + j], acc);
        hv[j] = acc;
    }
#pragma unroll
    for (int q = 0; q < HC / 8; ++q)
        hp[(size_t)n * (HC / 8) + q] = f_to_h8(hv + q * 8);
}

// ============ Layer-2 gather: H=4, fp16 rows (32 B), scores on the fly, W=8 ===
__global__ __launch_bounds__(256) void gat_gather2_kernel(
    const int* __restrict__ row_start, const int* __restrict__ degv,
    const int* __restrict__ col, const int4* __restrict__ hp,
    const float* __restrict__ a_src, const float* __restrict__ a_dst,
    const float* __restrict__ bias, float* __restrict__ xout, int N)
{
    int t = blockIdx.x * 256 + threadIdx.x;
    int n = t >> 3, lane = t & 7;
    if (n >= N) return;
    float As[16], Ad[16];
#pragma unroll
    for (int j = 0; j < 16; ++j) { As[j] = a_src[j]; Ad[j] = a_dst[j]; }
    float hn[16];
    h8_to_f(hp[(size_t)n * 2], hn);
    h8_to_f(hp[(size_t)n * 2 + 1], hn + 8);
    float ald[4];
#pragma unroll
    for (int hd = 0; hd < 4; ++hd) {
        float d = 0.0f;
#pragma unroll
        for (int c = 0; c < 4; ++c) d = fmaf(hn[hd * 4 + c], Ad[hd * 4 + c], d);
        ald[hd] = d;
    }
    float num[16], den[4];
    if (lane == 0) {
#pragma unroll
        for (int hd = 0; hd < 4; ++hd) {
            float a = 0.0f;
#pragma unroll
            for (int c = 0; c < 4; ++c) a = fmaf(hn[hd * 4 + c], As[hd * 4 + c], a);
            float w = __expf(lrelu(a + ald[hd]));
            den[hd] = w;
#pragma unroll
            for (int c = 0; c < 4; ++c) num[hd * 4 + c] = w * hn[hd * 4 + c];
        }
    } else {
#pragma unroll
        for (int j = 0; j < 16; ++j) num[j] = 0.0f;
#pragma unroll
        for (int hd = 0; hd < 4; ++hd) den[hd] = 0.0f;
    }
    int start = row_start[n];
    int end = start + degv[n];
    for (int e = start + lane; e < end; e += 8) {
        int s = col[e];
        if (s == n) continue;
        float hs[16];
        h8_to_f(hp[(size_t)s * 2], hs);
        h8_to_f(hp[(size_t)s * 2 + 1], hs + 8);
#pragma unroll
        for (int hd = 0; hd < 4; ++hd) {
            float a = 0.0f;
#pragma unroll
            for (int c = 0; c < 4; ++c) a = fmaf(hs[hd * 4 + c], As[hd * 4 + c], a);
            float w = __expf(lrelu(a + ald[hd]));
            den[hd] += w;
#pragma unroll
            for (int c = 0; c < 4; ++c) num[hd * 4 + c] = fmaf(w, hs[hd * 4 + c], num[hd * 4 + c]);
        }
    }
#pragma unroll
    for (int m = 1; m < 8; m <<= 1) {
#pragma unroll
        for (int hd = 0; hd < 4; ++hd) den[hd] += __shfl_xor(den[hd], m);
#pragma unroll
        for (int j = 0; j < 16; ++j) num[j] += __shfl_xor(num[j], m);
    }
    if (lane < 4) {
        float inv = 1.0f / den[lane];
        const float4 bb = ((const float4*)bias)[lane];
        float4 r;
        r.x = fmaxf(fmaf(num[lane * 4 + 0], inv, bb.x), 0.0f);
        r.y = fmaxf(fmaf(num[lane * 4 + 1], inv, bb.y), 0.0f);
        r.z = fmaxf(fmaf(num[lane * 4 + 2], inv, bb.z), 0.0f);
        r.w = fmaxf(fmaf(num[lane * 4 + 3], inv, bb.w), 0.0f);
        ((float4*)xout)[(size_t)n * 4 + lane] = r;
    }
}

// ============ Layer-3 gather: H=2, fp16 rows (16 B), W=4, fp16 x6 out =========
__global__ __launch_bounds__(256) void gat_gather3_kernel(
    const int* __restrict__ row_start, const int* __restrict__ degv,
    const int* __restrict__ col, const int4* __restrict__ hp,
    const float* __restrict__ a_src, const float* __restrict__ a_dst,
    const float* __restrict__ bias, int4* __restrict__ x6p, int N)
{
    int t = blockIdx.x * 256 + threadIdx.x;
    int n = t >> 2, lane = t & 3;
    if (n >= N) return;
    float As[8], Ad[8];
#pragma unroll
    for (int j = 0; j < 8; ++j) { As[j] = a_src[j]; Ad[j] = a_dst[j]; }
    float hn[8];
    h8_to_f(hp[n], hn);
    float ald[2];
#pragma unroll
    for (int hd = 0; hd < 2; ++hd) {
        float d = 0.0f;
#pragma unroll
        for (int c = 0; c < 4; ++c) d = fmaf(hn[hd * 4 + c], Ad[hd * 4 + c], d);
        ald[hd] = d;
    }
    float num[8], den[2];
    if (lane == 0) {
#pragma unroll
        for (int hd = 0; hd < 2; ++hd) {
            float a = 0.0f;
#pragma unroll
            for (int c = 0; c < 4; ++c) a = fmaf(hn[hd * 4 + c], As[hd * 4 + c], a);
            float w = __expf(lrelu(a + ald[hd]));
            den[hd] = w;
#pragma unroll
            for (int c = 0; c < 4; ++c) num[hd * 4 + c] = w * hn[hd * 4 + c];
        }
    } else {
#pragma unroll
        for (int j = 0; j < 8; ++j) num[j] = 0.0f;
        den[0] = den[1] = 0.0f;
    }
    int start = row_start[n];
    int end = start + degv[n];
    for (int e = start + lane; e < end; e += 4) {
        int s = col[e];
        if (s == n) continue;
        float hs[8];
        h8_to_f(hp[s], hs);
#pragma unroll
        for (int hd = 0; hd < 2; ++hd) {
            float a = 0.0f;
#pragma unroll
            for (int c = 0; c < 4; ++c) a = fmaf(hs[hd * 4 + c], As[hd * 4 + c], a);
            float w = __expf(lrelu(a + ald[hd]));
            den[hd] += w;
#pragma unroll
            for (int c = 0; c < 4; ++c) num[hd * 4 + c] = fmaf(w, hs[hd * 4 + c], num[hd * 4 + c]);
        }
    }
#pragma unroll
    for (int m = 1; m < 4; m <<= 1) {
        den[0] += __shfl_xor(den[0], m);
        den[1] += __shfl_xor(den[1], m);
#pragma unroll
        for (int j = 0; j < 8; ++j) num[j] += __shfl_xor(num[j], m);
    }
    if (lane == 0) {
        float o[8];
        float i0 = 1.0f / den[0], i1 = 1.0f / den[1];
#pragma unroll
        for (int c = 0; c < 4; ++c) {
            o[c]     = fmaxf(fmaf(num[c], i0, bias[c]), 0.0f);
            o[4 + c] = fmaxf(fmaf(num[4 + c], i1, bias[4 + c]), 0.0f);
        }
        x6p[n] = f_to_h8(o);
    }
}

// ============ Final scoring: by-src CSR, fp16 x6, W=4 =========================
__global__ __launch_bounds__(256) void score_gather_kernel(
    const int* __restrict__ row_start, const int* __restrict__ degv,
    const int* __restrict__ col, const int4* __restrict__ x6p,
    const float* __restrict__ lin2_w, float* __restrict__ out, int N)
{
    int t = blockIdx.x * 256 + threadIdx.x;
    int n = t >> 2, lane = t & 3;
    if (n >= N) return;
    float sx[8];
    h8_to_f(x6p[n], sx);
    float loc, r[8];
    int sc = 0;
    if (lane == 0) {
        loc = 0.0f;
#pragma unroll
        for (int j = 0; j < 8; ++j) { loc = fmaf(sx[j], sx[j], loc); r[j] = sx[j]; }
    } else {
        loc = 0.0f;
#pragma unroll
        for (int j = 0; j < 8; ++j) r[j] = 0.0f;
    }
    int start = row_start[n];
    int dg = degv[n];
    int end = start + dg;
    for (int e = start + lane; e < end; e += 4) {
        int d = col[e];
        if (d == n) { ++sc; continue; }
        float dx[8];
        h8_to_f(x6p[d], dx);
#pragma unroll
        for (int j = 0; j < 8; ++j) { loc = fmaf(sx[j], dx[j], loc); r[j] += dx[j]; }
    }
#pragma unroll
    for (int m = 1; m < 4; m <<= 1) {
        loc += __shfl_xor(loc, m);
        sc  += __shfl_xor(sc, m);
#pragma unroll
        for (int j = 0; j < 8; ++j) r[j] += __shfl_xor(r[j], m);
    }
    if (lane == 0) {
        float invd = 1.0f / (1.0f + (float)(dg - sc));
        float g = 0.0f;
#pragma unroll
        for (int j = 0; j < 8; ++j) g = fmaf(r[j], lin2_w[j], g);
        out[n] = (loc + g) * invd;
    }
}

extern "C" void kernel_launch(void* const* d_in, const int* in_sizes, int n_in,
                              void* d_out, int out_size, void* d_ws, size_t ws_size,
                              hipStream_t stream)
{
    const float* x1     = (const float*)d_in[0];
    const int*   ei     = (const int*)d_in[2];
    const float* lin1_w = (const float*)d_in[4];
    const float* lin1_b = (const float*)d_in[5];
    const float* lin2_w = (const float*)d_in[6];
    const float* W1     = (const float*)d_in[7];
    const float* a_src1 = (const float*)d_in[8];
    const float* a_dst1 = (const float*)d_in[9];
    const float* b1     = (const float*)d_in[10];
    const float* W2     = (const float*)d_in[11];
    const float* a_src2 = (const float*)d_in[12];
    const float* a_dst2 = (const float*)d_in[13];
    const float* b2     = (const float*)d_in[14];
    const float* W3     = (const float*)d_in[15];
    const float* a_src3 = (const float*)d_in[16];
    const float* a_dst3 = (const float*)d_in[17];
    const float* b3     = (const float*)d_in[18];
    float* out = (float*)d_out;

    const int N = in_sizes[0] / 7;   // 100000
    const int E = in_sizes[2] / 2;   // 3200000
    const int* src = ei;
    const int* dst = ei + E;

    const int npr = (N + P - 1) / P;                  // 391 nodes per range
    const unsigned int mg = (unsigned int)((0x100000000ULL + npr - 1) / (unsigned long long)npr);

    // ---- workspace layout ----
    size_t Ns = (size_t)N, Es = (size_t)E;
    int* ideg_dst = (int*)d_ws;
    int* ideg_src = ideg_dst + Ns;
    int* irow_dst = ideg_src + Ns;
    int* irow_src = irow_dst + Ns;
    int* gcount   = irow_src + Ns;        // 2P = 512 ints
    int* iebase   = gcount + 2 * P;       // 512 ints
    int* icol_dst = iebase + 2 * P;
    int* icol_src = icol_dst + Es;
    float* f = (float*)(icol_src + Es);   // 80N float region
    // staging (2 * P * CAP uint32 = 7.58M words = 75.8N) aliases f; dies after build
    unsigned int* stgd = (unsigned int*)f;
    unsigned int* stgs = stgd + (size_t)P * CAP;
    // float/fp16 buffers, born after build (disjoint; total 65N <= 80N):
    float* h0  = f;                        // [0, N)
    float* x3  = f + Ns;                   // [N, 33N)      fp32 [N,32]
    int4*  h2p = (int4*)(f + 33 * Ns);     // [33N, 41N)    fp16 [N,16] (32 B rows)
    float* x4  = f + 41 * Ns;              // [41N, 57N)    fp32 [N,16]
    int4*  h3p = (int4*)(f + 57 * Ns);     // [57N, 61N)    fp16 [N,8]  (16 B rows)
    int4*  x6p = (int4*)(f + 61 * Ns);     // [61N, 65N)    fp16 [N,8]

    const int TB = 256;
    const int gN = (N + TB - 1) / TB;
    const int g8 = (8 * N + TB - 1) / TB;
    const int g4 = (4 * N + TB - 1) / TB;
    const int chsz = (((E + PB - 1) / PB) + 3) & ~3;   // 4-multiple for int4

    // ---- CSR build: 2-phase bucket sort, block-private write sectors ----
    hipMemsetAsync(gcount, 0, 2 * P * sizeof(int), stream);
    part_kernel<<<PB, 256, 0, stream>>>(src, dst, stgd, stgs, gcount, E, npr, mg, chsz);
    ebase_kernel<<<1, 2 * P, 0, stream>>>(gcount, iebase);
    build_kernel<<<2 * P, 256, 0, stream>>>(stgd, stgs, gcount, iebase,
                                            icol_dst, icol_src,
                                            ideg_dst, ideg_src,
                                            irow_dst, irow_src, N, npr);

    // ---- Layer 1: rank-1 fast path ----
    l1h0_kernel<<<gN, TB, 0, stream>>>(x1, lin1_w, lin1_b, h0, N);
    gat_gather1_kernel<<<g8, TB, 0, stream>>>(irow_dst, ideg_dst, icol_dst,
                                              h0, W1, a_src1, a_dst1, b1, x3, N);

    // ---- Layer 2: [N,32] -> [N,16], H=4 ----
    gat_node_f16_kernel<32, 16><<<gN, TB, 0, stream>>>(x3, W2, h2p, N);
    gat_gather2_kernel<<<g8, TB, 0, stream>>>(irow_dst, ideg_dst, icol_dst,
                                              h2p, a_src2, a_dst2, b2, x4, N);

    // ---- Layer 3: [N,16] -> [N,8], H=2 ----
    gat_node_f16_kernel<16, 8><<<gN, TB, 0, stream>>>(x4, W3, h3p, N);
    gat_gather3_kernel<<<g4, TB, 0, stream>>>(irow_dst, ideg_dst, icol_dst,
                                              h3p, a_src3, a_dst3, b3, x6p, N);

    // ---- Final scoring (by-src CSR) ----
    score_gather_kernel<<<g4, TB, 0, stream>>>(irow_src, ideg_src, icol_src,
                                               x6p, lin2_w, out, N);
}